// Round 2
// baseline (1522.681 us; speedup 1.0000x reference)
//
#include <hip/hip_runtime.h>
#include <math.h>

#define BDIM 2
#define SDIM 4096
#define DMODEL 512
#define NHEAD 8
#define DHEAD 64
#define MROWS (BDIM * SDIM)  // 8192

// ---------------------------------------------------------------------------
// Tiled fp32 GEMM: out[M,512] = X[M,512] @ W[512,512] + bias
// BM=64, BN=64, BK=16, 256 threads, 4x4 microtile per thread.
// HEAD_SPLIT=1: write to [B,H,S,D] layout (n0 is 64-aligned so each n-tile is
// exactly one head).
// ---------------------------------------------------------------------------
template <int HEAD_SPLIT>
__global__ __launch_bounds__(256) void gemm512_kernel(
    const float* __restrict__ X, const float* __restrict__ W,
    const float* __restrict__ bias, float* __restrict__ out) {
  __shared__ float As[16][64];  // [k][m]
  __shared__ float Bs[16][64];  // [k][n]

  const int tid = threadIdx.x;
  const int tm = tid >> 4;    // 0..15
  const int tn = tid & 15;    // 0..15
  const int m0 = blockIdx.x * 64;
  const int n0 = blockIdx.y * 64;

  float c[4][4];
#pragma unroll
  for (int i = 0; i < 4; i++)
#pragma unroll
    for (int j = 0; j < 4; j++) c[i][j] = 0.f;

  for (int k0 = 0; k0 < DMODEL; k0 += 16) {
    // Load X tile 64x16 (1024 floats, 4 per thread) -> As[k][m] (transposed)
    {
      const int r = tid >> 2;          // 0..63 (m within tile)
      const int kb = (tid & 3) * 4;    // 0,4,8,12
      const float4 x4 =
          *(const float4*)(X + (size_t)(m0 + r) * DMODEL + k0 + kb);
      As[kb + 0][r] = x4.x;
      As[kb + 1][r] = x4.y;
      As[kb + 2][r] = x4.z;
      As[kb + 3][r] = x4.w;
    }
    // Load W tile 16x64 (1024 floats, 4 per thread) -> Bs[k][n]
    {
      const int kr = tid >> 4;         // 0..15
      const int nb = (tid & 15) * 4;   // 0..60
      *(float4*)&Bs[kr][nb] =
          *(const float4*)(W + (size_t)(k0 + kr) * DMODEL + n0 + nb);
    }
    __syncthreads();

#pragma unroll
    for (int kk = 0; kk < 16; kk++) {
      const float4 a4 = *(const float4*)&As[kk][tm * 4];
      const float4 b4 = *(const float4*)&Bs[kk][tn * 4];
      const float a[4] = {a4.x, a4.y, a4.z, a4.w};
      const float b[4] = {b4.x, b4.y, b4.z, b4.w};
#pragma unroll
      for (int i = 0; i < 4; i++)
#pragma unroll
        for (int j = 0; j < 4; j++) c[i][j] = fmaf(a[i], b[j], c[i][j]);
    }
    __syncthreads();
  }

  const float4 bb4 = *(const float4*)(bias + n0 + tn * 4);
  const float bb[4] = {bb4.x, bb4.y, bb4.z, bb4.w};

#pragma unroll
  for (int i = 0; i < 4; i++) {
    const int m = m0 + tm * 4 + i;
    const float4 o4 = make_float4(c[i][0] + bb[0], c[i][1] + bb[1],
                                  c[i][2] + bb[2], c[i][3] + bb[3]);
    if (HEAD_SPLIT) {
      const int bidx = m >> 12;   // m / 4096
      const int s = m & 4095;
      const int h = n0 >> 6;      // whole tile is one head
      const int d = tn * 4;
      *(float4*)(out +
                 (((size_t)(bidx * NHEAD + h) * SDIM + s) * DHEAD + d)) = o4;
    } else {
      *(float4*)(out + (size_t)m * DMODEL + n0 + tn * 4) = o4;
    }
  }
}

// ---------------------------------------------------------------------------
// Flash-style attention, fp32. One block per (b, h, 64-row Q tile).
// Online softmax over 64-wide K tiles. K and V share one LDS buffer
// (K as [d][kc] during S-compute, then V as [kc][d] during PV).
// Tile loads: 64x64 = 4096 floats = 256 threads x 4 float4 chunks.
// ctx written in [B, S, H*D] layout so the output projection reads row-major.
// ---------------------------------------------------------------------------
__global__ __launch_bounds__(256) void flash_attn_kernel(
    const float* __restrict__ qh, const float* __restrict__ kh,
    const float* __restrict__ vh, const float* __restrict__ mask,
    float* __restrict__ ctx) {
  __shared__ float Qs[64][64];   // [d][q]   (transposed)
  __shared__ float KVs[64][64];  // K: [d][kc]; later V: [kc][d]
  __shared__ float Ps[64][64];   // [kc][q]  (S^T, then P^T)
  __shared__ float mrow[64], lrow[64], alph[64];
  __shared__ float maskadd[64];
  __shared__ float pmax[4][64], psum[4][64];

  const int tid = threadIdx.x;
  const int tm = tid >> 4;   // 0..15
  const int tn = tid & 15;   // 0..15
  const int q0 = blockIdx.x * 64;
  const int h = blockIdx.y;
  const int b = blockIdx.z;

  const size_t base = (size_t)(b * NHEAD + h) * SDIM * DHEAD;
  const float* Q = qh + base;
  const float* K = kh + base;
  const float* V = vh + base;
  const float* mb = mask + (size_t)b * SDIM;

  // Load Q tile transposed: Qs[d][q]. 4096 floats: 4 chunks of 4/thread.
#pragma unroll
  for (int c = 0; c < 4; c++) {
    const int idx = (c << 8) + tid;      // 0..1023
    const int r = idx >> 4;              // q row 0..63
    const int db = (idx & 15) * 4;       // d 0..60
    const float4 v4 = *(const float4*)(Q + (size_t)(q0 + r) * DHEAD + db);
    Qs[db + 0][r] = v4.x;
    Qs[db + 1][r] = v4.y;
    Qs[db + 2][r] = v4.z;
    Qs[db + 3][r] = v4.w;
  }
  if (tid < 64) {
    mrow[tid] = -1e30f;
    lrow[tid] = 0.f;
  }

  float o[4][4];
#pragma unroll
  for (int i = 0; i < 4; i++)
#pragma unroll
    for (int j = 0; j < 4; j++) o[i][j] = 0.f;

  const int qrow = tid & 63;
  const int part = tid >> 6;  // one wave per part

  for (int kt = 0; kt < SDIM / 64; kt++) {
    const int k0 = kt * 64;

    // Load K tile transposed: KVs[d][kc]; load mask adds
#pragma unroll
    for (int c = 0; c < 4; c++) {
      const int idx = (c << 8) + tid;
      const int r = idx >> 4;            // kc 0..63
      const int db = (idx & 15) * 4;     // d 0..60
      const float4 k4 = *(const float4*)(K + (size_t)(k0 + r) * DHEAD + db);
      KVs[db + 0][r] = k4.x;
      KVs[db + 1][r] = k4.y;
      KVs[db + 2][r] = k4.z;
      KVs[db + 3][r] = k4.w;
    }
    if (tid < 64) maskadd[tid] = mb[k0 + tid] * (-1e9f);
    __syncthreads();

    // S = (Q K^T) * 0.125 + mask  -> Ps[kc][q]
    float s[4][4];
#pragma unroll
    for (int i = 0; i < 4; i++)
#pragma unroll
      for (int j = 0; j < 4; j++) s[i][j] = 0.f;

#pragma unroll 8
    for (int d = 0; d < 64; d++) {
      const float4 a4 = *(const float4*)&Qs[d][tm * 4];
      const float4 b4 = *(const float4*)&KVs[d][tn * 4];
      const float a[4] = {a4.x, a4.y, a4.z, a4.w};
      const float bv[4] = {b4.x, b4.y, b4.z, b4.w};
#pragma unroll
      for (int i = 0; i < 4; i++)
#pragma unroll
        for (int j = 0; j < 4; j++) s[i][j] = fmaf(a[i], bv[j], s[i][j]);
    }
    __syncthreads();  // all reads of KVs (K) done before V overwrites

#pragma unroll
    for (int j = 0; j < 4; j++) {
      const float ma = maskadd[tn * 4 + j];
#pragma unroll
      for (int i = 0; i < 4; i++)
        Ps[tn * 4 + j][tm * 4 + i] = s[i][j] * 0.125f + ma;
    }
    // Load V tile: KVs[kc][d] (natural layout)
#pragma unroll
    for (int c = 0; c < 4; c++) {
      const int idx = (c << 8) + tid;
      const int r = idx >> 4;            // kc 0..63
      const int db = (idx & 15) * 4;     // d 0..60
      *(float4*)&KVs[r][db] =
          *(const float4*)(V + (size_t)(k0 + r) * DHEAD + db);
    }
    __syncthreads();

    // Softmax phase 1: partial max over this wave's 16 kc
    {
      float lm = -1e30f;
      for (int kc = part * 16; kc < part * 16 + 16; kc++)
        lm = fmaxf(lm, Ps[kc][qrow]);
      pmax[part][qrow] = lm;
    }
    __syncthreads();

    // Softmax phase 2: exp + partial sum (reads OLD mrow; part 0 updates after)
    const float mold = mrow[qrow];
    const float mnew =
        fmaxf(mold, fmaxf(fmaxf(pmax[0][qrow], pmax[1][qrow]),
                          fmaxf(pmax[2][qrow], pmax[3][qrow])));
    const float al = __expf(mold - mnew);
    {
      float ls = 0.f;
      for (int kc = part * 16; kc < part * 16 + 16; kc++) {
        const float p = __expf(Ps[kc][qrow] - mnew);
        Ps[kc][qrow] = p;
        ls += p;
      }
      psum[part][qrow] = ls;
    }
    __syncthreads();

    if (part == 0) {
      lrow[qrow] = lrow[qrow] * al +
                   (psum[0][qrow] + psum[1][qrow] + psum[2][qrow] + psum[3][qrow]);
      mrow[qrow] = mnew;
      alph[qrow] = al;
    }
    __syncthreads();

    // Rescale O and accumulate P @ V
#pragma unroll
    for (int i = 0; i < 4; i++) {
      const float a = alph[tm * 4 + i];
#pragma unroll
      for (int j = 0; j < 4; j++) o[i][j] *= a;
    }
#pragma unroll 8
    for (int kc = 0; kc < 64; kc++) {
      const float4 p4 = *(const float4*)&Ps[kc][tm * 4];
      const float4 v4 = *(const float4*)&KVs[kc][tn * 4];
      const float p[4] = {p4.x, p4.y, p4.z, p4.w};
      const float vv[4] = {v4.x, v4.y, v4.z, v4.w};
#pragma unroll
      for (int i = 0; i < 4; i++)
#pragma unroll
        for (int j = 0; j < 4; j++) o[i][j] = fmaf(p[i], vv[j], o[i][j]);
    }
    __syncthreads();  // before next tile overwrites KVs/Ps/maskadd
  }

  // Normalize and write ctx in [B, S, H*D] layout
#pragma unroll
  for (int i = 0; i < 4; i++) {
    const int q = tm * 4 + i;
    const float inv = 1.f / lrow[q];
    const float4 o4 = make_float4(o[i][0] * inv, o[i][1] * inv, o[i][2] * inv,
                                  o[i][3] * inv);
    *(float4*)(ctx + ((size_t)b * SDIM + q0 + q) * DMODEL + h * DHEAD +
               tn * 4) = o4;
  }
}

// ---------------------------------------------------------------------------
extern "C" void kernel_launch(void* const* d_in, const int* in_sizes, int n_in,
                              void* d_out, int out_size, void* d_ws,
                              size_t ws_size, hipStream_t stream) {
  const float* q = (const float*)d_in[0];
  const float* k = (const float*)d_in[1];
  const float* v = (const float*)d_in[2];
  const float* mask = (const float*)d_in[3];
  const float* Wq = (const float*)d_in[4];
  const float* bq = (const float*)d_in[5];
  const float* Wk = (const float*)d_in[6];
  const float* bk = (const float*)d_in[7];
  const float* Wv = (const float*)d_in[8];
  const float* bv = (const float*)d_in[9];
  const float* Wo = (const float*)d_in[10];
  const float* bo = (const float*)d_in[11];
  float* out = (float*)d_out;

  float* ws = (float*)d_ws;
  const size_t SZ = (size_t)MROWS * DMODEL;  // 4,194,304 floats = 16 MB
  float* qh = ws;
  float* kh = ws + SZ;
  float* vh = ws + 2 * SZ;
  float* ctx = ws + 3 * SZ;

  const dim3 gproj(MROWS / 64, DMODEL / 64);  // 128 x 8
  gemm512_kernel<1><<<gproj, 256, 0, stream>>>(q, Wq, bq, qh);
  gemm512_kernel<1><<<gproj, 256, 0, stream>>>(k, Wk, bk, kh);
  gemm512_kernel<1><<<gproj, 256, 0, stream>>>(v, Wv, bv, vh);

  const dim3 gattn(SDIM / 64, NHEAD, BDIM);  // 64 x 8 x 2
  flash_attn_kernel<<<gattn, 256, 0, stream>>>(qh, kh, vh, mask, ctx);

  gemm512_kernel<0><<<gproj, 256, 0, stream>>>(ctx, Wo, bo, out);
}

// Round 3
// 706.727 us; speedup vs baseline: 2.1546x; 2.1546x over previous
//
#include <hip/hip_runtime.h>
#include <math.h>

#define BDIM 2
#define SDIM 4096
#define DMODEL 512
#define NHEAD 8
#define DHEAD 64
#define MROWS (BDIM * SDIM)  // 8192

typedef __attribute__((ext_vector_type(8))) short short8;
typedef __attribute__((ext_vector_type(4))) float f32x4;

#define MFMA16(a, b, c) __builtin_amdgcn_mfma_f32_16x16x32_bf16((a), (b), (c), 0, 0, 0)

// Truncation split: x = h + l with h = top 16 bits (exact subtraction).
__device__ inline void bf16_split(float x, short& h, short& l) {
  unsigned u = __float_as_uint(x);
  h = (short)(u >> 16);
  float hf = __uint_as_float(u & 0xffff0000u);
  l = (short)(__float_as_uint(x - hf) >> 16);
}

// ---------------------------------------------------------------------------
// Tiled fp32 GEMM: out[M,512] = X[M,512] @ W[512,512] + bias
// MODE 0: fp32 out [M, DM].  MODE 1: bf16 h/l split outputs in [B,H,S,D].
// ---------------------------------------------------------------------------
template <int MODE>
__global__ __launch_bounds__(256) void gemm512_kernel(
    const float* __restrict__ X, const float* __restrict__ W,
    const float* __restrict__ bias, float* __restrict__ out,
    short* __restrict__ oh, short* __restrict__ ol) {
  __shared__ float As[16][64];  // [k][m]
  __shared__ float Bs[16][64];  // [k][n]

  const int tid = threadIdx.x;
  const int tm = tid >> 4;
  const int tn = tid & 15;
  const int m0 = blockIdx.x * 64;
  const int n0 = blockIdx.y * 64;

  float c[4][4];
#pragma unroll
  for (int i = 0; i < 4; i++)
#pragma unroll
    for (int j = 0; j < 4; j++) c[i][j] = 0.f;

  for (int k0 = 0; k0 < DMODEL; k0 += 16) {
    {
      const int r = tid >> 2;
      const int kb = (tid & 3) * 4;
      const float4 x4 =
          *(const float4*)(X + (size_t)(m0 + r) * DMODEL + k0 + kb);
      As[kb + 0][r] = x4.x;
      As[kb + 1][r] = x4.y;
      As[kb + 2][r] = x4.z;
      As[kb + 3][r] = x4.w;
    }
    {
      const int kr = tid >> 4;
      const int nb = (tid & 15) * 4;
      *(float4*)&Bs[kr][nb] =
          *(const float4*)(W + (size_t)(k0 + kr) * DMODEL + n0 + nb);
    }
    __syncthreads();

#pragma unroll
    for (int kk = 0; kk < 16; kk++) {
      const float4 a4 = *(const float4*)&As[kk][tm * 4];
      const float4 b4 = *(const float4*)&Bs[kk][tn * 4];
      const float a[4] = {a4.x, a4.y, a4.z, a4.w};
      const float b[4] = {b4.x, b4.y, b4.z, b4.w};
#pragma unroll
      for (int i = 0; i < 4; i++)
#pragma unroll
        for (int j = 0; j < 4; j++) c[i][j] = fmaf(a[i], b[j], c[i][j]);
    }
    __syncthreads();
  }

  const float4 bb4 = *(const float4*)(bias + n0 + tn * 4);
  const float bb[4] = {bb4.x, bb4.y, bb4.z, bb4.w};

#pragma unroll
  for (int i = 0; i < 4; i++) {
    const int m = m0 + tm * 4 + i;
    float v[4];
#pragma unroll
    for (int j = 0; j < 4; j++) v[j] = c[i][j] + bb[j];
    if (MODE == 1) {
      const int bidx = m >> 12;
      const int s = m & 4095;
      const int hh = n0 >> 6;
      const int d = tn * 4;
      const size_t off =
          ((size_t)(bidx * NHEAD + hh) * SDIM + s) * DHEAD + d;
      short4 hv, lv;
      bf16_split(v[0], hv.x, lv.x);
      bf16_split(v[1], hv.y, lv.y);
      bf16_split(v[2], hv.z, lv.z);
      bf16_split(v[3], hv.w, lv.w);
      *(short4*)(oh + off) = hv;
      *(short4*)(ol + off) = lv;
    } else {
      *(float4*)(out + (size_t)m * DMODEL + n0 + tn * 4) =
          make_float4(v[0], v[1], v[2], v[3]);
    }
  }
}

// ---------------------------------------------------------------------------
// Flash attention, bf16x3 split-precision MFMA (16x16x32_bf16).
// Block: 256 thr = 4 waves; wave owns 32 q-rows (block = 128 q-rows).
// K-loop: 32 keys/tile. Q h/l A-frags persistent in registers.
// LDS: K [kc][d] pitch 72, V^T [d][kc] pitch 40, P [q][kc] pitch 40 (h+l each).
// ---------------------------------------------------------------------------
#define KP 72
#define VP 40
#define PP 40

__global__ __launch_bounds__(256, 2) void flash_attn_kernel(
    const short* __restrict__ qhh, const short* __restrict__ qhl,
    const short* __restrict__ khh, const short* __restrict__ khl,
    const short* __restrict__ vhh, const short* __restrict__ vhl,
    const float* __restrict__ mask, float* __restrict__ ctx) {
  __shared__ short Ksh[32 * KP], Ksl[32 * KP];
  __shared__ short Vth[64 * VP], Vtl[64 * VP];
  __shared__ short Psh[128 * PP], Psl[128 * PP];

  const int tid = threadIdx.x;
  const int lane = tid & 63;
  const int w = tid >> 6;        // wave 0..3
  const int lane15 = lane & 15;  // n / m index within MFMA tile
  const int quad = (lane >> 4) & 3;
  const int q0 = blockIdx.x * 128;
  const int h = blockIdx.y;
  const int b = blockIdx.z;

  const size_t base = (size_t)(b * NHEAD + h) * SDIM * DHEAD;
  const short* Qh = qhh + base;
  const short* Ql = qhl + base;
  const short* Kh = khh + base;
  const short* Kl = khl + base;
  const short* Vh = vhh + base;
  const short* Vl = vhl + base;
  const float* mb = mask + (size_t)b * SDIM;

  // Persistent Q A-fragments: [mt][ks] (m = lane15, k = quad*8 + j)
  short8 qfh[2][2], qfl[2][2];
#pragma unroll
  for (int mt = 0; mt < 2; mt++) {
    const size_t row = q0 + w * 32 + mt * 16 + lane15;
#pragma unroll
    for (int ks = 0; ks < 2; ks++) {
      qfh[mt][ks] = *(const short8*)(Qh + row * DHEAD + ks * 32 + quad * 8);
      qfl[mt][ks] = *(const short8*)(Ql + row * DHEAD + ks * 32 + quad * 8);
    }
  }

  f32x4 o[2][4];
#pragma unroll
  for (int mt = 0; mt < 2; mt++)
#pragma unroll
    for (int dt = 0; dt < 4; dt++) o[mt][dt] = (f32x4){0.f, 0.f, 0.f, 0.f};
  float m_run[2][4], l_run[2][4];
#pragma unroll
  for (int mt = 0; mt < 2; mt++)
#pragma unroll
    for (int r = 0; r < 4; r++) {
      m_run[mt][r] = -1e30f;
      l_run[mt][r] = 0.f;
    }

  short8 onesb;
#pragma unroll
  for (int j = 0; j < 8; j++) onesb[j] = (short)0x3F80;  // bf16 1.0

  // Staging index maps (chosen for LDS bank spread)
  const int kr = tid & 31;          // K: kc row
  const int kd8 = (tid >> 5) * 8;   // K: d offset
  const int vkc = tid & 31;         // V: kc (column in Vt)
  const int vd8 = (tid >> 5) * 8;   // V: d rows

  for (int kt = 0; kt < SDIM / 32; kt++) {
    const int k0 = kt * 32;

    // ---- Stage K [kc][d] and V^T [d][kc] ----
    *(short8*)&Ksh[kr * KP + kd8] =
        *(const short8*)(Kh + (size_t)(k0 + kr) * DHEAD + kd8);
    *(short8*)&Ksl[kr * KP + kd8] =
        *(const short8*)(Kl + (size_t)(k0 + kr) * DHEAD + kd8);
    {
      short8 v8h = *(const short8*)(Vh + (size_t)(k0 + vkc) * DHEAD + vd8);
      short8 v8l = *(const short8*)(Vl + (size_t)(k0 + vkc) * DHEAD + vd8);
#pragma unroll
      for (int i = 0; i < 8; i++) {
        Vth[(vd8 + i) * VP + vkc] = v8h[i];
        Vtl[(vd8 + i) * VP + vkc] = v8l[i];
      }
    }
    float mv[2];
#pragma unroll
    for (int nt = 0; nt < 2; nt++)
      mv[nt] = mb[k0 + nt * 16 + lane15] * (-1e9f);
    __syncthreads();

    // ---- S = Q K^T (bf16x3) ----
    f32x4 s[2][2];
#pragma unroll
    for (int mt = 0; mt < 2; mt++)
#pragma unroll
      for (int nt = 0; nt < 2; nt++) {
        f32x4 acc = (f32x4){0.f, 0.f, 0.f, 0.f};
#pragma unroll
        for (int ks = 0; ks < 2; ks++) {
          const int koff = (nt * 16 + lane15) * KP + ks * 32 + quad * 8;
          const short8 kbh = *(const short8*)&Ksh[koff];
          const short8 kbl = *(const short8*)&Ksl[koff];
          acc = MFMA16(qfh[mt][ks], kbh, acc);
          acc = MFMA16(qfh[mt][ks], kbl, acc);
          acc = MFMA16(qfl[mt][ks], kbh, acc);
        }
#pragma unroll
        for (int r = 0; r < 4; r++) acc[r] = acc[r] * 0.125f + mv[nt];
        s[mt][nt] = acc;
      }

    // ---- Row max (butterfly over lane bits 0..3) ----
    float t0[2][4];
#pragma unroll
    for (int mt = 0; mt < 2; mt++)
#pragma unroll
      for (int r = 0; r < 4; r++)
        t0[mt][r] = fmaxf(s[mt][0][r], s[mt][1][r]);
#pragma unroll
    for (int off = 1; off < 16; off <<= 1)
#pragma unroll
      for (int mt = 0; mt < 2; mt++)
#pragma unroll
        for (int r = 0; r < 4; r++)
          t0[mt][r] = fmaxf(t0[mt][r], __shfl_xor(t0[mt][r], off, 64));

    float alpha[2][4];
#pragma unroll
    for (int mt = 0; mt < 2; mt++)
#pragma unroll
      for (int r = 0; r < 4; r++) {
        const float mnew = fmaxf(m_run[mt][r], t0[mt][r]);
        alpha[mt][r] = __expf(m_run[mt][r] - mnew);
        m_run[mt][r] = mnew;
      }

    // ---- exp + split P to LDS ----
#pragma unroll
    for (int mt = 0; mt < 2; mt++)
#pragma unroll
      for (int nt = 0; nt < 2; nt++)
#pragma unroll
        for (int r = 0; r < 4; r++) {
          const float p = __expf(s[mt][nt][r] - m_run[mt][r]);
          const int addr =
              (w * 32 + mt * 16 + quad * 4 + r) * PP + nt * 16 + lane15;
          short ph, pl;
          bf16_split(p, ph, pl);
          Psh[addr] = ph;
          Psl[addr] = pl;
        }
    // Same-wave LDS write->read: compiler inserts lgkmcnt wait; no barrier.

    // ---- P A-frags + row-sum via MFMA(P, ones) ----
    short8 pah[2], pal[2];
    f32x4 rs[2];
#pragma unroll
    for (int mt = 0; mt < 2; mt++) {
      const int poff = (w * 32 + mt * 16 + lane15) * PP + quad * 8;
      pah[mt] = *(const short8*)&Psh[poff];
      pal[mt] = *(const short8*)&Psl[poff];
      f32x4 racc = (f32x4){0.f, 0.f, 0.f, 0.f};
      racc = MFMA16(pah[mt], onesb, racc);
      racc = MFMA16(pal[mt], onesb, racc);
      rs[mt] = racc;
    }

    // ---- update l, rescale O ----
#pragma unroll
    for (int mt = 0; mt < 2; mt++)
#pragma unroll
      for (int r = 0; r < 4; r++)
        l_run[mt][r] = l_run[mt][r] * alpha[mt][r] + rs[mt][r];
#pragma unroll
    for (int mt = 0; mt < 2; mt++)
#pragma unroll
      for (int dt = 0; dt < 4; dt++)
#pragma unroll
        for (int r = 0; r < 4; r++) o[mt][dt][r] *= alpha[mt][r];

    // ---- O += P V (bf16x3) ----
#pragma unroll
    for (int dt = 0; dt < 4; dt++) {
      const int voff = (dt * 16 + lane15) * VP + quad * 8;
      const short8 vbh = *(const short8*)&Vth[voff];
      const short8 vbl = *(const short8*)&Vtl[voff];
#pragma unroll
      for (int mt = 0; mt < 2; mt++) {
        o[mt][dt] = MFMA16(pah[mt], vbh, o[mt][dt]);
        o[mt][dt] = MFMA16(pah[mt], vbl, o[mt][dt]);
        o[mt][dt] = MFMA16(pal[mt], vbh, o[mt][dt]);
      }
    }
    __syncthreads();  // protect Ks/Vt before next staging
  }

  // ---- normalize + write ctx [B, S, H*D] fp32 ----
  float inv[2][4];
#pragma unroll
  for (int mt = 0; mt < 2; mt++)
#pragma unroll
    for (int r = 0; r < 4; r++) inv[mt][r] = 1.f / l_run[mt][r];
#pragma unroll
  for (int mt = 0; mt < 2; mt++)
#pragma unroll
    for (int dt = 0; dt < 4; dt++)
#pragma unroll
      for (int r = 0; r < 4; r++) {
        const int q = q0 + w * 32 + mt * 16 + quad * 4 + r;
        const int col = h * DHEAD + dt * 16 + lane15;
        ctx[((size_t)b * SDIM + q) * DMODEL + col] = o[mt][dt][r] * inv[mt][r];
      }
}

// ---------------------------------------------------------------------------
extern "C" void kernel_launch(void* const* d_in, const int* in_sizes, int n_in,
                              void* d_out, int out_size, void* d_ws,
                              size_t ws_size, hipStream_t stream) {
  const float* q = (const float*)d_in[0];
  const float* k = (const float*)d_in[1];
  const float* v = (const float*)d_in[2];
  const float* mask = (const float*)d_in[3];
  const float* Wq = (const float*)d_in[4];
  const float* bq = (const float*)d_in[5];
  const float* Wk = (const float*)d_in[6];
  const float* bk = (const float*)d_in[7];
  const float* Wv = (const float*)d_in[8];
  const float* bv = (const float*)d_in[9];
  const float* Wo = (const float*)d_in[10];
  const float* bo = (const float*)d_in[11];
  float* out = (float*)d_out;

  const size_t SZ = (size_t)MROWS * DMODEL;  // 4,194,304 elements
  short* ws16 = (short*)d_ws;
  short* q_h = ws16 + 0 * SZ;
  short* q_l = ws16 + 1 * SZ;
  short* k_h = ws16 + 2 * SZ;
  short* k_l = ws16 + 3 * SZ;
  short* v_h = ws16 + 4 * SZ;
  short* v_l = ws16 + 5 * SZ;
  float* ctx = (float*)((char*)d_ws + 6 * SZ * sizeof(short));  // 48 MB off

  const dim3 gproj(MROWS / 64, DMODEL / 64);  // 128 x 8
  gemm512_kernel<1><<<gproj, 256, 0, stream>>>(q, Wq, bq, nullptr, q_h, q_l);
  gemm512_kernel<1><<<gproj, 256, 0, stream>>>(k, Wk, bk, nullptr, k_h, k_l);
  gemm512_kernel<1><<<gproj, 256, 0, stream>>>(v, Wv, bv, nullptr, v_h, v_l);

  const dim3 gattn(SDIM / 128, NHEAD, BDIM);  // 32 x 8 x 2
  flash_attn_kernel<<<gattn, 256, 0, stream>>>(q_h, q_l, k_h, k_l, v_h, v_l,
                                               mask, ctx);

  gemm512_kernel<0><<<gproj, 256, 0, stream>>>(ctx, Wo, bo, out, nullptr,
                                               nullptr);
}